// Round 14
// baseline (108.181 us; speedup 1.0000x reference)
//
#include <hip/hip_runtime.h>

#define N_TEX 65536
#define C 16
#define U 4194304
#define ILP 4

typedef float    f32x4 __attribute__((ext_vector_type(4)));
typedef int      i32x4 __attribute__((ext_vector_type(4)));
typedef _Float16 f16x4 __attribute__((ext_vector_type(4)));

// ---------------------------------------------------------------------------
// Convert fp32 texture (4 MiB) -> fp16 (2 MiB) in d_ws.
// ---------------------------------------------------------------------------
__global__ __launch_bounds__(256) void convert_kernel(
    const f32x4* __restrict__ in, f16x4* __restrict__ out16)
{
    const int i = blockIdx.x * 256 + threadIdx.x;
    f32x4 v = __builtin_nontemporal_load(&in[i]);
    f16x4 h;
    h.x = (_Float16)v.x; h.y = (_Float16)v.y;
    h.z = (_Float16)v.z; h.w = (_Float16)v.w;
    out16[i] = h;
}

// ---------------------------------------------------------------------------
// GATHER-WARM: exact D1 body with REP=1. Same grid as the sampler; block b
// performs EXACTLY the random gathers + plain (cached) param loads that
// sampler block b will issue, with NO stores (asm sink keeps loads live).
// Theory: gathers are only expensive when concurrent with the 256 MiB write
// stream (HBM read/write turnaround + L3 churn). A write-free full-gather
// pass re-establishes texture+param residency; the following sampler's
// gathers then ride L2/L3 while its stores own HBM -> write-roofline pass.
// This is the ONE state D1 created that no warm variant so far reproduced.
// ---------------------------------------------------------------------------
__global__ __launch_bounds__(256) void gather_warm_kernel(
    const f16x4* __restrict__ tex16, const float* __restrict__ param)
{
    const int NT  = (U * 4) / ILP;
    const int tid = blockIdx.x * 256 + threadIdx.x;
    const int q   = tid & 3;
    float ax = 0.f, ay = 0.f, az = 0.f, aw = 0.f;
#pragma unroll
    for (int k = 0; k < ILP; ++k) {
        const float p = param[(tid + k * NT) >> 2];     // plain cached load
        const float t = p * (float)(N_TEX - 1);
        const float f = fminf(fmaxf(floorf(t), 0.0f), (float)(N_TEX - 1));
        const float w = t - f;
        const int i0 = (int)f;
        const int i1 = min(i0 + 1, N_TEX - 1);
        const f16x4 a = tex16[i0 * 4 + q];
        const f16x4 b = tex16[i1 * 4 + q];
        ax += (float)a.x * (1.0f - w) + (float)b.x * w;
        ay += (float)a.y * (1.0f - w) + (float)b.y * w;
        az += (float)a.z * (1.0f - w) + (float)b.z * w;
        aw += (float)a.w * (1.0f - w) + (float)b.w * w;
    }
    asm volatile("" :: "v"(ax), "v"(ay), "v"(az), "v"(aw));
}

// ---------------------------------------------------------------------------
// Sampler: EXACT R7 kernel -- fp16 texture, 4 lanes/sample, ILP=4,
// nontemporal param loads + output stores.
// ---------------------------------------------------------------------------
__global__ __launch_bounds__(256) void sampler1d_kernel(
    const f16x4* __restrict__ tex16, const float* __restrict__ param,
    f32x4* __restrict__ out)
{
    const int NT  = (U * 4) / ILP;
    const int tid = blockIdx.x * 256 + threadIdx.x;
    const int q   = tid & 3;

    float p[ILP];
#pragma unroll
    for (int k = 0; k < ILP; ++k)
        p[k] = __builtin_nontemporal_load(&param[(tid + k * NT) >> 2]);

    float w[ILP];
    f16x4 a[ILP], b[ILP];
#pragma unroll
    for (int k = 0; k < ILP; ++k) {
        const float t = p[k] * (float)(N_TEX - 1);
        float f = floorf(t);
        f = fminf(fmaxf(f, 0.0f), (float)(N_TEX - 1));
        const int i0 = (int)f;
        const int i1 = min(i0 + 1, N_TEX - 1);
        w[k] = t - f;
        a[k] = tex16[i0 * 4 + q];
        b[k] = tex16[i1 * 4 + q];
    }

#pragma unroll
    for (int k = 0; k < ILP; ++k) {
        const float wk = w[k], iw = 1.0f - wk;
        f32x4 r;
        r.x = (float)a[k].x * iw + (float)b[k].x * wk;
        r.y = (float)a[k].y * iw + (float)b[k].y * wk;
        r.z = (float)a[k].z * iw + (float)b[k].z * wk;
        r.w = (float)a[k].w * iw + (float)b[k].w * wk;
        __builtin_nontemporal_store(r, &out[tid + k * NT]);
    }
}

extern "C" void kernel_launch(void* const* d_in, const int* in_sizes, int n_in,
                              void* d_out, int out_size, void* d_ws, size_t ws_size,
                              hipStream_t stream) {
    const f32x4* tex32 = (const f32x4*)d_in[0];
    const float* param = (const float*)d_in[1];
    f32x4*       out   = (f32x4*)d_out;
    f16x4*       tex16 = (f16x4*)d_ws;     // 2 MiB scratch

    const int total_thr = (U * 4) / ILP;   // 4,194,304 -> 16,384 blocks

    convert_kernel<<<(N_TEX * C / 4) / 256, 256, 0, stream>>>(tex32, tex16);
    gather_warm_kernel<<<total_thr / 256, 256, 0, stream>>>(tex16, param);
    sampler1d_kernel<<<total_thr / 256, 256, 0, stream>>>(tex16, param, out);
}